// Round 7
// baseline (232.828 us; speedup 1.0000x reference)
//
#include <hip/hip_runtime.h>
#include <hip/hip_bf16.h>
#include <math.h>

// Problem constants
#define B_    4
#define C_IN_ 128
#define N_    2048
#define NSEL_ 1024
#define H_    4

typedef __bf16 bf16;
typedef __bf16 bf16x2 __attribute__((ext_vector_type(2)));
typedef __bf16 bf16x4 __attribute__((ext_vector_type(4)));
typedef __bf16 bf16x8 __attribute__((ext_vector_type(8)));
typedef float  f32x4  __attribute__((ext_vector_type(4)));

// ---------------------------------------------------------------------------
// Kernel 0 (prep): W fp32 -> bf16 (Wbf, 4x256x128); inverse permutation.
// ---------------------------------------------------------------------------
__global__ __launch_bounds__(256) void prep_kernel(
    const int* __restrict__ isel, const int* __restrict__ idrp,
    const float* __restrict__ Wq, const float* __restrict__ Wk,
    const float* __restrict__ Wv, const float* __restrict__ Ws,
    int* __restrict__ inv, bf16* __restrict__ Wbf)
{
    const int blk = blockIdx.x;
    if (blk < 128) {
        int e = blk * 256 + threadIdx.x;       // 0..32767 float4s
        int which = e >> 13, idx = e & 8191;
        const float* Wx = (which == 0) ? Wq : (which == 1) ? Wk
                        : (which == 2) ? Wv : Ws;
        float4 v = *(const float4*)(Wx + (size_t)idx * 4);
        bf16x4 o; o[0] = (bf16)v.x; o[1] = (bf16)v.y; o[2] = (bf16)v.z; o[3] = (bf16)v.w;
        *(bf16x4*)(Wbf + (size_t)which * 32768 + (size_t)idx * 4) = o;
    } else {
        int g = (blk - 128) * 256 + threadIdx.x;   // 0..8191
        int b = g >> 11, j = g & (N_ - 1);
        int pos = (j < NSEL_) ? isel[b * NSEL_ + j] : idrp[b * NSEL_ + (j - NSEL_)];
        inv[b * N_ + (pos & (N_ - 1))] = j;
    }
}

// ---------------------------------------------------------------------------
// Kernel 1: QKV + skip MFMA GEMM. One block = (ntile, which, row-half, b):
// 128 rows x 64 cols, K=128. Wave w owns 32 rows. grid (32, 8, B).
// ---------------------------------------------------------------------------
#define XSTR 136

__global__ __launch_bounds__(256) void qkv_mfma_kernel(
    const float* __restrict__ pcd, const float* __restrict__ sel,
    const float* __restrict__ drop, const bf16* __restrict__ Wbf,
    bf16* __restrict__ qT, bf16* __restrict__ kT, bf16* __restrict__ vN,
    float* __restrict__ out)
{
    const int ntile = blockIdx.x;
    const int which = blockIdx.y >> 1;   // 0=Q 1=K 2=V 3=skip
    const int rh    = blockIdx.y & 1;    // 128-row half
    const int b     = blockIdx.z;
    const int tid   = threadIdx.x;
    const int w     = tid >> 6;
    const int lane  = tid & 63;
    const int quad  = lane >> 4;
    const int lc    = lane & 15;
    const int n0    = ntile * 64;

    __shared__ __align__(16) bf16 xT[64 * XSTR];

    const float* srcp; int rstride;
    if (which == 3)      { srcp = pcd  + (size_t)b * C_IN_ * N_ + n0;              rstride = N_;    }
    else if (ntile < 16) { srcp = sel  + (size_t)b * C_IN_ * NSEL_ + n0;           rstride = NSEL_; }
    else                 { srcp = drop + (size_t)b * C_IN_ * NSEL_ + (n0 - NSEL_); rstride = NSEL_; }

    // Stage x fp32 [c][n] -> bf16 xT [n][c ^ swz]; swz = ((n>>2)&3)<<3.
    #pragma unroll
    for (int k = 0; k < 8; ++k) {
        int e  = tid + k * 256;
        int c  = e >> 4, nq = e & 15;
        float4 v = *(const float4*)(srcp + (size_t)c * rstride + nq * 4);
        int cc = c ^ ((nq & 3) << 3);
        xT[(nq * 4 + 0) * XSTR + cc] = (bf16)v.x;
        xT[(nq * 4 + 1) * XSTR + cc] = (bf16)v.y;
        xT[(nq * 4 + 2) * XSTR + cc] = (bf16)v.z;
        xT[(nq * 4 + 3) * XSTR + cc] = (bf16)v.w;
    }
    __syncthreads();

    const bf16* wbase = Wbf + (size_t)which * 256 * 128;
    const int rbase = rh * 128 + w * 32;     // wave's first output row (of 256)

    f32x4 acc[2][4];
    #pragma unroll
    for (int mt = 0; mt < 2; ++mt)
        #pragma unroll
        for (int nt = 0; nt < 4; ++nt) acc[mt][nt] = (f32x4){0.f, 0.f, 0.f, 0.f};

    #pragma unroll
    for (int kq = 0; kq < 4; ++kq) {
        bf16x8 A[2], Bf[4];
        #pragma unroll
        for (int mt = 0; mt < 2; ++mt)
            A[mt] = *(const bf16x8*)(wbase + (size_t)(rbase + mt * 16 + lc) * 128 + kq * 32 + quad * 8);
        #pragma unroll
        for (int nt = 0; nt < 4; ++nt) {
            int row = nt * 16 + lc;
            int col = (kq * 32 + quad * 8) ^ (((row >> 2) & 3) << 3);
            Bf[nt] = *(const bf16x8*)&xT[row * XSTR + col];
        }
        #pragma unroll
        for (int mt = 0; mt < 2; ++mt)
            #pragma unroll
            for (int nt = 0; nt < 4; ++nt)
                acc[mt][nt] = __builtin_amdgcn_mfma_f32_16x16x32_bf16(A[mt], Bf[nt], acc[mt][nt], 0, 0, 0);
    }

    // Epilogue. C layout: row(m)=quad*4+r, col(n)=lc.
    #pragma unroll
    for (int mt = 0; mt < 2; ++mt) {
        #pragma unroll
        for (int nt = 0; nt < 4; ++nt) {
            #pragma unroll
            for (int r = 0; r < 4; ++r) {
                int o256 = rbase + mt * 16 + quad * 4 + r;
                int n    = n0 + nt * 16 + lc;
                float val = acc[mt][nt][r];
                if (which == 0) {
                    int h = o256 >> 6, d = o256 & 63;
                    qT[((size_t)(b * H_ + h) * N_ + n) * 64 + d] = (bf16)(val * 0.125f);
                } else if (which == 1) {
                    int h = o256 >> 6, d = o256 & 63;
                    kT[((size_t)(b * H_ + h) * N_ + n) * 64 + d] = (bf16)val;
                } else if (which == 2) {
                    vN[((size_t)b * 256 + o256) * N_ + n] = (bf16)val;
                } else {
                    out[((size_t)b * 256 + o256) * N_ + n] = val;
                }
            }
        }
    }
}

// ---------------------------------------------------------------------------
// Kernel 2: key-split flash attention (no max; chunk results are additive).
// Each block: 64 queries x nc keys; writes chunk-normalized O (bf16) + chunk
// denominator s_c (fp32). grid (32, H*KS, B): y -> (h = y&3, chunk c = y>>2).
// ---------------------------------------------------------------------------
#define PLDS_STRIDE 88

__global__ __launch_bounds__(256) void attn_kernel(
    const bf16* __restrict__ qT, const bf16* __restrict__ kT,
    const bf16* __restrict__ vN, bf16* __restrict__ Opart,
    float* __restrict__ S_ws, int nc)
{
    const int ntile = blockIdx.x;
    const int h     = blockIdx.y & 3;
    const int c     = blockIdx.y >> 2;
    const int b     = blockIdx.z;
    const int tid   = threadIdx.x;
    const int w     = tid >> 6;
    const int lane  = tid & 63;
    const int quad  = lane >> 4;
    const int lc    = lane & 15;
    const int n0    = ntile * 64;
    const int bh    = b * H_ + h;
    const int m_start = c * nc;
    const int nsteps  = nc >> 6;

    __shared__ __align__(16) bf16 p_lds[4 * 2 * 16 * PLDS_STRIDE];

    const bf16* qbase = qT + (size_t)bh * N_ * 64;
    const bf16* kbase = kT + (size_t)bh * N_ * 64;
    const bf16* vbase = vN + ((size_t)b * 256 + h * 64) * (size_t)N_;

    const bf16* qp = qbase + (size_t)(n0 + w * 16 + lc) * 64 + quad * 8;
    bf16x8 aq0 = *(const bf16x8*)(qp);
    bf16x8 aq1 = *(const bf16x8*)(qp + 32);

    f32x4 accO[4];
    #pragma unroll
    for (int i = 0; i < 4; ++i) accO[i] = (f32x4){0.f, 0.f, 0.f, 0.f};
    float psum[4] = {0.f, 0.f, 0.f, 0.f};

    bf16x8 kf[4][2];
    #pragma unroll
    for (int mt = 0; mt < 4; ++mt) {
        const bf16* kp = kbase + (size_t)(m_start + mt * 16 + lc) * 64 + quad * 8;
        kf[mt][0] = *(const bf16x8*)(kp);
        kf[mt][1] = *(const bf16x8*)(kp + 32);
    }

    for (int step = 0; step < nsteps; ++step) {
        const int m0 = m_start + step * 64;
        bf16* pw = &p_lds[(w * 2 + (step & 1)) * 16 * PLDS_STRIDE];

        // ---- S = (Q/8)^T K ----
        f32x4 accS[4];
        #pragma unroll
        for (int mt = 0; mt < 4; ++mt) {
            f32x4 z = (f32x4){0.f, 0.f, 0.f, 0.f};
            z = __builtin_amdgcn_mfma_f32_16x16x32_bf16(aq0, kf[mt][0], z, 0, 0, 0);
            z = __builtin_amdgcn_mfma_f32_16x16x32_bf16(aq1, kf[mt][1], z, 0, 0, 0);
            accS[mt] = z;
        }

        // ---- V loads (this step) + K loads (next step) ----
        bf16x8 vf[4][2];
        #pragma unroll
        for (int dvt = 0; dvt < 4; ++dvt) {
            const bf16* vp = vbase + (size_t)(dvt * 16 + lc) * N_ + m0 + quad * 8;
            vf[dvt][0] = *(const bf16x8*)(vp);
            vf[dvt][1] = *(const bf16x8*)(vp + 32);
        }
        const int mn = (step < nsteps - 1) ? m0 + 64 : m_start;
        #pragma unroll
        for (int mt = 0; mt < 4; ++mt) {
            const bf16* kp = kbase + (size_t)(mn + mt * 16 + lc) * 64 + quad * 8;
            kf[mt][0] = *(const bf16x8*)(kp);
            kf[mt][1] = *(const bf16x8*)(kp + 32);
        }

        // ---- P = exp(S), per-lane row partial sums ----
        #pragma unroll
        for (int r = 0; r < 4; ++r) {
            float s = 0.f;
            #pragma unroll
            for (int mt = 0; mt < 4; ++mt) {
                float p = __expf(accS[mt][r]);
                accS[mt][r] = p;
                s += p;
            }
            psum[r] += s;
        }

        // ---- P: C layout -> per-wave LDS strip -> A layout ----
        #pragma unroll
        for (int mt = 0; mt < 4; ++mt)
            #pragma unroll
            for (int r = 0; r < 4; ++r)
                pw[(quad * 4 + r) * PLDS_STRIDE + mt * 16 + lc] = (bf16)accS[mt][r];
        bf16x8 ap0 = *(const bf16x8*)(pw + lc * PLDS_STRIDE + quad * 8);
        bf16x8 ap1 = *(const bf16x8*)(pw + lc * PLDS_STRIDE + 32 + quad * 8);

        // ---- O += P * V^T ----
        #pragma unroll
        for (int dvt = 0; dvt < 4; ++dvt) {
            accO[dvt] = __builtin_amdgcn_mfma_f32_16x16x32_bf16(ap0, vf[dvt][0], accO[dvt], 0, 0, 0);
            accO[dvt] = __builtin_amdgcn_mfma_f32_16x16x32_bf16(ap1, vf[dvt][1], accO[dvt], 0, 0, 0);
        }
    }

    // ---- chunk denominators + chunk-normalized O ----
    float inv[4];
    #pragma unroll
    for (int r = 0; r < 4; ++r) {
        float s = psum[r];
        #pragma unroll
        for (int off = 1; off < 16; off <<= 1)
            s += __shfl_xor(s, off, 64);
        inv[r] = 1.f / s;
        int n = n0 + w * 16 + quad * 4 + r;
        if (lc == 0)
            S_ws[((size_t)(c * B_ + b) * H_ + h) * N_ + n] = s;
    }

    #pragma unroll
    for (int r = 0; r < 4; ++r) {
        int n = n0 + w * 16 + quad * 4 + r;
        #pragma unroll
        for (int dvt = 0; dvt < 4; ++dvt) {
            int o = h * 64 + dvt * 16 + lc;
            Opart[((size_t)(c * B_ + b) * N_ + n) * 256 + o] = (bf16)(accO[dvt][r] * inv[r]);
        }
    }
}

// ---------------------------------------------------------------------------
// Kernel 3: merge chunks + permutation scatter + skip add (coalesced RMW).
// out[b,o,pos] += sum_c w_c * Opart[c][b,inv[pos],o], w_c = s_c / sum s.
// grid (32 pos-tiles, 4 og(=h), B), 256 thr.
// ---------------------------------------------------------------------------
__global__ __launch_bounds__(256) void scatter_kernel(
    const bf16* __restrict__ Opart, const float* __restrict__ S_ws,
    const int* __restrict__ inv, float* __restrict__ out, int KS)
{
    const int ptile = blockIdx.x;
    const int og    = blockIdx.y;     // == head h
    const int b     = blockIdx.z;
    const int tid   = threadIdx.x;
    const int p0    = ptile * 64;

    __shared__ __align__(16) bf16 lds[64 * 72];
    __shared__ float wls[4][64];
    __shared__ int   jrow[64];

    if (tid < 64) {
        int row = tid;
        int j = inv[b * N_ + p0 + row] & (N_ - 1);
        jrow[row] = j;
        float sv[4]; float denom = 0.f;
        #pragma unroll
        for (int c = 0; c < 4; ++c) {
            sv[c] = (c < KS) ? S_ws[((size_t)(c * B_ + b) * H_ + og) * N_ + j] : 0.f;
            denom += sv[c];
        }
        float id = 1.f / denom;
        #pragma unroll
        for (int c = 0; c < 4; ++c) wls[c][row] = sv[c] * id;
    }
    __syncthreads();

    #pragma unroll
    for (int k = 0; k < 2; ++k) {
        int e = tid + k * 256;
        int row = e >> 3, seg = e & 7;
        int j = jrow[row];
        float a8[8];
        #pragma unroll
        for (int i = 0; i < 8; ++i) a8[i] = 0.f;
        for (int c = 0; c < KS; ++c) {
            bf16x8 v = *(const bf16x8*)(Opart + ((size_t)(c * B_ + b) * N_ + j) * 256 + og * 64 + seg * 8);
            float wgt = wls[c][row];
            #pragma unroll
            for (int i = 0; i < 8; ++i) a8[i] += wgt * (float)v[i];
        }
        bf16x8 o8;
        #pragma unroll
        for (int i = 0; i < 8; ++i) o8[i] = (bf16)a8[i];
        *(bf16x8*)&lds[row * 72 + seg * 8] = o8;
    }
    __syncthreads();

    const int pl  = tid & 63;
    const int og2 = tid >> 6;
    #pragma unroll
    for (int k = 0; k < 8; ++k) {
        int o_loc = og2 * 16 + k * 2;
        bf16x2 v2 = *(const bf16x2*)&lds[pl * 72 + o_loc];
        int o = og * 64 + o_loc;
        size_t a = ((size_t)b * 256 + o) * N_ + p0 + pl;
        out[a]      += (float)v2[0];
        out[a + N_] += (float)v2[1];
    }
}

// ---------------------------------------------------------------------------
extern "C" void kernel_launch(void* const* d_in, const int* in_sizes, int n_in,
                              void* d_out, int out_size, void* d_ws, size_t ws_size,
                              hipStream_t stream) {
    const float* pcd  = (const float*)d_in[0];
    const float* sel  = (const float*)d_in[1];
    const float* drop = (const float*)d_in[2];
    const int*   isel = (const int*)d_in[3];
    const int*   idrp = (const int*)d_in[4];
    const float* Wq   = (const float*)d_in[5];
    const float* Wk   = (const float*)d_in[6];
    const float* Wv   = (const float*)d_in[7];
    const float* Ws   = (const float*)d_in[8];
    float* out = (float*)d_out;

    const size_t MB = 1024 * 1024;
    // ws: qT 4MB | kT 4MB | vN 4MB | Opart KS*4MB | S_ws KS*128KB | inv 32KB
    auto need = [&](int ks) {
        return 12 * MB + (size_t)ks * 4 * MB + (size_t)ks * 128 * 1024 + 32 * 1024;
    };
    int KS = (ws_size >= need(4)) ? 4 : (ws_size >= need(2)) ? 2 : 1;

    char*  ws    = (char*)d_ws;
    bf16*  qT    = (bf16*)(ws);
    bf16*  kT    = (bf16*)(ws + 4 * MB);
    bf16*  vN    = (bf16*)(ws + 8 * MB);
    bf16*  Opart = (bf16*)(ws + 12 * MB);
    float* S_ws  = (float*)(ws + 12 * MB + (size_t)KS * 4 * MB);
    int*   inv   = (int*)(ws + 12 * MB + (size_t)KS * 4 * MB + (size_t)KS * 128 * 1024);
    bf16*  Wbf   = Opart;   // aliases Opart chunk 0: read by qkv BEFORE attn writes

    prep_kernel<<<dim3(160), 256, 0, stream>>>(isel, idrp, Wq, Wk, Wv, Ws, inv, Wbf);
    qkv_mfma_kernel<<<dim3(32, 8, B_), 256, 0, stream>>>(pcd, sel, drop, Wbf,
                                                         qT, kT, vN, out);
    attn_kernel<<<dim3(32, H_ * KS, B_), 256, 0, stream>>>(qT, kT, vN, Opart,
                                                           S_ws, N_ / KS);
    scatter_kernel<<<dim3(32, 4, B_), 256, 0, stream>>>(Opart, S_ws, inv, out, KS);
}

// Round 8
// 143.238 us; speedup vs baseline: 1.6255x; 1.6255x over previous
//
#include <hip/hip_runtime.h>
#include <hip/hip_bf16.h>
#include <math.h>

// Problem constants
#define B_    4
#define C_IN_ 128
#define N_    2048
#define NSEL_ 1024
#define H_    4
#define KS_   2            // key-split chunks (nc = 1024 keys, 16 tiles of 64)

typedef __bf16 bf16;
typedef __bf16 bf16x2 __attribute__((ext_vector_type(2)));
typedef __bf16 bf16x4 __attribute__((ext_vector_type(4)));
typedef __bf16 bf16x8 __attribute__((ext_vector_type(8)));
typedef float  f32x4  __attribute__((ext_vector_type(4)));

// ---------------------------------------------------------------------------
// Kernel 0 (prep): W fp32 -> bf16 (Wbf, 4x256x128); inverse permutation.
// ---------------------------------------------------------------------------
__global__ __launch_bounds__(256) void prep_kernel(
    const int* __restrict__ isel, const int* __restrict__ idrp,
    const float* __restrict__ Wq, const float* __restrict__ Wk,
    const float* __restrict__ Wv, const float* __restrict__ Ws,
    int* __restrict__ inv, bf16* __restrict__ Wbf)
{
    const int blk = blockIdx.x;
    if (blk < 128) {
        int e = blk * 256 + threadIdx.x;
        int which = e >> 13, idx = e & 8191;
        const float* Wx = (which == 0) ? Wq : (which == 1) ? Wk
                        : (which == 2) ? Wv : Ws;
        float4 v = *(const float4*)(Wx + (size_t)idx * 4);
        bf16x4 o; o[0] = (bf16)v.x; o[1] = (bf16)v.y; o[2] = (bf16)v.z; o[3] = (bf16)v.w;
        *(bf16x4*)(Wbf + (size_t)which * 32768 + (size_t)idx * 4) = o;
    } else {
        int g = (blk - 128) * 256 + threadIdx.x;
        int b = g >> 11, j = g & (N_ - 1);
        int pos = (j < NSEL_) ? isel[b * NSEL_ + j] : idrp[b * NSEL_ + (j - NSEL_)];
        inv[b * N_ + (pos & (N_ - 1))] = j;
    }
}

// ---------------------------------------------------------------------------
// Kernel 1: QKV + skip MFMA GEMM (grid (32, 8, B), 128 rows x 64 cols, K=128).
//   qT : (bh, n, 64) bf16, Q pre-scaled 1/8
//   kTt: (bh, tile, r=key&63, d)  bf16 -- 8KB contiguous tiles for LDS staging
//   vTt: (bh, tile, dv, m=key&63) bf16 -- 8KB contiguous tiles
//   skip: fp32 straight into d_out.
// ---------------------------------------------------------------------------
#define XSTR 136

__global__ __launch_bounds__(256) void qkv_mfma_kernel(
    const float* __restrict__ pcd, const float* __restrict__ sel,
    const float* __restrict__ drop, const bf16* __restrict__ Wbf,
    bf16* __restrict__ qT, bf16* __restrict__ kTt, bf16* __restrict__ vTt,
    float* __restrict__ out)
{
    const int ntile = blockIdx.x;
    const int which = blockIdx.y >> 1;   // 0=Q 1=K 2=V 3=skip
    const int rh    = blockIdx.y & 1;    // 128-row half
    const int b     = blockIdx.z;
    const int tid   = threadIdx.x;
    const int w     = tid >> 6;
    const int lane  = tid & 63;
    const int quad  = lane >> 4;
    const int lc    = lane & 15;
    const int n0    = ntile * 64;

    __shared__ __align__(16) bf16 xT[64 * XSTR];

    const float* srcp; int rstride;
    if (which == 3)      { srcp = pcd  + (size_t)b * C_IN_ * N_ + n0;              rstride = N_;    }
    else if (ntile < 16) { srcp = sel  + (size_t)b * C_IN_ * NSEL_ + n0;           rstride = NSEL_; }
    else                 { srcp = drop + (size_t)b * C_IN_ * NSEL_ + (n0 - NSEL_); rstride = NSEL_; }

    // Stage x fp32 [c][n] -> bf16 xT [n][c ^ swz]; swz = ((n>>2)&3)<<3.
    #pragma unroll
    for (int k = 0; k < 8; ++k) {
        int e  = tid + k * 256;
        int c  = e >> 4, nq = e & 15;
        float4 v = *(const float4*)(srcp + (size_t)c * rstride + nq * 4);
        int cc = c ^ ((nq & 3) << 3);
        xT[(nq * 4 + 0) * XSTR + cc] = (bf16)v.x;
        xT[(nq * 4 + 1) * XSTR + cc] = (bf16)v.y;
        xT[(nq * 4 + 2) * XSTR + cc] = (bf16)v.z;
        xT[(nq * 4 + 3) * XSTR + cc] = (bf16)v.w;
    }
    __syncthreads();

    const bf16* wbase = Wbf + (size_t)which * 256 * 128;
    const int rbase = rh * 128 + w * 32;

    f32x4 acc[2][4];
    #pragma unroll
    for (int mt = 0; mt < 2; ++mt)
        #pragma unroll
        for (int nt = 0; nt < 4; ++nt) acc[mt][nt] = (f32x4){0.f, 0.f, 0.f, 0.f};

    #pragma unroll
    for (int kq = 0; kq < 4; ++kq) {
        bf16x8 A[2], Bf[4];
        #pragma unroll
        for (int mt = 0; mt < 2; ++mt)
            A[mt] = *(const bf16x8*)(wbase + (size_t)(rbase + mt * 16 + lc) * 128 + kq * 32 + quad * 8);
        #pragma unroll
        for (int nt = 0; nt < 4; ++nt) {
            int row = nt * 16 + lc;
            int col = (kq * 32 + quad * 8) ^ (((row >> 2) & 3) << 3);
            Bf[nt] = *(const bf16x8*)&xT[row * XSTR + col];
        }
        #pragma unroll
        for (int mt = 0; mt < 2; ++mt)
            #pragma unroll
            for (int nt = 0; nt < 4; ++nt)
                acc[mt][nt] = __builtin_amdgcn_mfma_f32_16x16x32_bf16(A[mt], Bf[nt], acc[mt][nt], 0, 0, 0);
    }

    // Epilogue. C layout: row(m)=quad*4+r, col(n)=lc.
    #pragma unroll
    for (int mt = 0; mt < 2; ++mt) {
        #pragma unroll
        for (int nt = 0; nt < 4; ++nt) {
            #pragma unroll
            for (int r = 0; r < 4; ++r) {
                int o256 = rbase + mt * 16 + quad * 4 + r;
                int n    = n0 + nt * 16 + lc;
                int rloc = nt * 16 + lc;           // n & 63
                float val = acc[mt][nt][r];
                if (which == 0) {
                    int h = o256 >> 6, d = o256 & 63;
                    qT[((size_t)(b * H_ + h) * N_ + n) * 64 + d] = (bf16)(val * 0.125f);
                } else if (which == 1) {
                    int h = o256 >> 6, d = o256 & 63;
                    kTt[(((size_t)(b * H_ + h) * 32 + ntile) << 12) | (rloc << 6) | d] = (bf16)val;
                } else if (which == 2) {
                    int h = o256 >> 6, dv = o256 & 63;
                    vTt[(((size_t)(b * H_ + h) * 32 + ntile) << 12) | (dv << 6) | rloc] = (bf16)val;
                } else {
                    out[((size_t)b * 256 + o256) * N_ + n] = val;
                }
            }
        }
    }
}

// ---------------------------------------------------------------------------
// Kernel 2: key-split flash attention, K/V staged through LDS (m97-style
// 2-barrier pipeline: loads for tile s+1 issued right after barriers, land
// during compute of tile s). XCD-aware block swizzle keeps each (b,h)'s
// K/V in one XCD's L2. No online max (exp safe; chunks additive).
// grid: 1024 blocks x 256 thr. id -> xcd=id&7, bh=(id&7)+8*((id>>3)&1),
// ntile=(id>>4)&31, chunk c=id>>9.
// ---------------------------------------------------------------------------
#define PSTR 88
#define KVSTR 72   // LDS row stride for 64-elem tile rows (pad: banks spread)

__global__ __launch_bounds__(256) void attn_kernel(
    const bf16* __restrict__ qT, const bf16* __restrict__ kTt,
    const bf16* __restrict__ vTt, bf16* __restrict__ Opart,
    float* __restrict__ S_ws)
{
    const int id    = blockIdx.x;
    const int bh    = (id & 7) + 8 * ((id >> 3) & 1);
    const int ntile = (id >> 4) & 31;
    const int c     = id >> 9;           // 0..KS_-1
    const int b     = bh >> 2;
    const int h     = bh & 3;
    const int tid   = threadIdx.x;
    const int w     = tid >> 6;
    const int lane  = tid & 63;
    const int quad  = lane >> 4;
    const int lc    = lane & 15;
    const int n0    = ntile * 64;

    __shared__ __align__(16) bf16 sK[64 * KVSTR];     // 9216 B
    __shared__ __align__(16) bf16 sV[64 * KVSTR];     // 9216 B
    __shared__ __align__(16) bf16 p_lds[4 * 16 * PSTR]; // 11264 B

    bf16* pw = &p_lds[w * 16 * PSTR];

    // Q fragments (A layout)
    const bf16* qp = qT + ((size_t)bh * N_ + n0 + w * 16 + lc) * 64 + quad * 8;
    bf16x8 aq0 = *(const bf16x8*)(qp);
    bf16x8 aq1 = *(const bf16x8*)(qp + 32);

    const bf16* kbase = kTt + (((size_t)bh * 32 + c * 16) << 12);
    const bf16* vbase = vTt + (((size_t)bh * 32 + c * 16) << 12);

    // staging map: thread tid handles 16B chunks tid and tid+256 of each 8KB tile
    const int l0 = (tid >> 3) * KVSTR + (tid & 7) * 8;
    const int l1 = ((tid >> 3) + 32) * KVSTR + (tid & 7) * 8;

    // prologue: issue loads for tile 0
    bf16x8 ldK0 = *(const bf16x8*)(kbase + tid * 8);
    bf16x8 ldK1 = *(const bf16x8*)(kbase + 2048 + tid * 8);
    bf16x8 ldV0 = *(const bf16x8*)(vbase + tid * 8);
    bf16x8 ldV1 = *(const bf16x8*)(vbase + 2048 + tid * 8);

    f32x4 accO[4];
    #pragma unroll
    for (int i = 0; i < 4; ++i) accO[i] = (f32x4){0.f, 0.f, 0.f, 0.f};
    float psum[4] = {0.f, 0.f, 0.f, 0.f};

    for (int s = 0; s < 16; ++s) {
        __syncthreads();   // consumers of previous tile done; staged loads drained
        *(bf16x8*)&sK[l0] = ldK0;
        *(bf16x8*)&sK[l1] = ldK1;
        *(bf16x8*)&sV[l0] = ldV0;
        *(bf16x8*)&sV[l1] = ldV1;
        __syncthreads();   // tile visible to all waves

        if (s < 15) {      // issue next tile's loads; land during compute below
            const bf16* kg = kbase + ((size_t)(s + 1) << 12);
            const bf16* vg = vbase + ((size_t)(s + 1) << 12);
            ldK0 = *(const bf16x8*)(kg + tid * 8);
            ldK1 = *(const bf16x8*)(kg + 2048 + tid * 8);
            ldV0 = *(const bf16x8*)(vg + tid * 8);
            ldV1 = *(const bf16x8*)(vg + 2048 + tid * 8);
        }

        // ---- S = (Q/8)^T K from LDS ----
        f32x4 accS[4];
        #pragma unroll
        for (int mt = 0; mt < 4; ++mt) {
            const int rb = (mt * 16 + lc) * KVSTR + quad * 8;
            bf16x8 k0 = *(const bf16x8*)&sK[rb];
            bf16x8 k1 = *(const bf16x8*)&sK[rb + 32];
            f32x4 z = (f32x4){0.f, 0.f, 0.f, 0.f};
            z = __builtin_amdgcn_mfma_f32_16x16x32_bf16(aq0, k0, z, 0, 0, 0);
            z = __builtin_amdgcn_mfma_f32_16x16x32_bf16(aq1, k1, z, 0, 0, 0);
            accS[mt] = z;
        }

        // ---- P = exp(S), per-lane row partial sums ----
        #pragma unroll
        for (int r = 0; r < 4; ++r) {
            float sum = 0.f;
            #pragma unroll
            for (int mt = 0; mt < 4; ++mt) {
                float p = __expf(accS[mt][r]);
                accS[mt][r] = p;
                sum += p;
            }
            psum[r] += sum;
        }

        // ---- P: C layout -> per-wave LDS strip -> A layout (no barrier) ----
        #pragma unroll
        for (int mt = 0; mt < 4; ++mt)
            #pragma unroll
            for (int r = 0; r < 4; ++r)
                pw[(quad * 4 + r) * PSTR + mt * 16 + lc] = (bf16)accS[mt][r];
        bf16x8 ap0 = *(const bf16x8*)(pw + lc * PSTR + quad * 8);
        bf16x8 ap1 = *(const bf16x8*)(pw + lc * PSTR + 32 + quad * 8);

        // ---- O += P * V^T from LDS ----
        #pragma unroll
        for (int dvt = 0; dvt < 4; ++dvt) {
            const int rb = (dvt * 16 + lc) * KVSTR + quad * 8;
            bf16x8 v0 = *(const bf16x8*)&sV[rb];
            bf16x8 v1 = *(const bf16x8*)&sV[rb + 32];
            accO[dvt] = __builtin_amdgcn_mfma_f32_16x16x32_bf16(ap0, v0, accO[dvt], 0, 0, 0);
            accO[dvt] = __builtin_amdgcn_mfma_f32_16x16x32_bf16(ap1, v1, accO[dvt], 0, 0, 0);
        }
    }

    // ---- chunk denominators + chunk-normalized O ----
    float inv[4];
    #pragma unroll
    for (int r = 0; r < 4; ++r) {
        float s = psum[r];
        #pragma unroll
        for (int off = 1; off < 16; off <<= 1)
            s += __shfl_xor(s, off, 64);
        inv[r] = 1.f / s;
        int n = n0 + w * 16 + quad * 4 + r;
        if (lc == 0)
            S_ws[((size_t)(c * B_ + b) * H_ + h) * N_ + n] = s;
    }

    #pragma unroll
    for (int r = 0; r < 4; ++r) {
        int n = n0 + w * 16 + quad * 4 + r;
        #pragma unroll
        for (int dvt = 0; dvt < 4; ++dvt) {
            int o = h * 64 + dvt * 16 + lc;
            Opart[((size_t)(c * B_ + b) * N_ + n) * 256 + o] = (bf16)(accO[dvt][r] * inv[r]);
        }
    }
}

// ---------------------------------------------------------------------------
// Kernel 3: merge KS chunks + permutation scatter + skip add (coalesced RMW).
// grid (32 pos-tiles, 4 og(=h), B), 256 thr.
// ---------------------------------------------------------------------------
__global__ __launch_bounds__(256) void scatter_kernel(
    const bf16* __restrict__ Opart, const float* __restrict__ S_ws,
    const int* __restrict__ inv, float* __restrict__ out)
{
    const int ptile = blockIdx.x;
    const int og    = blockIdx.y;     // == head h
    const int b     = blockIdx.z;
    const int tid   = threadIdx.x;
    const int p0    = ptile * 64;

    __shared__ __align__(16) bf16 lds[64 * 72];
    __shared__ float wls[KS_][64];
    __shared__ int   jrow[64];

    if (tid < 64) {
        int row = tid;
        int j = inv[b * N_ + p0 + row] & (N_ - 1);
        jrow[row] = j;
        float sv[KS_]; float denom = 0.f;
        #pragma unroll
        for (int c = 0; c < KS_; ++c) {
            sv[c] = S_ws[((size_t)(c * B_ + b) * H_ + og) * N_ + j];
            denom += sv[c];
        }
        float id = 1.f / denom;
        #pragma unroll
        for (int c = 0; c < KS_; ++c) wls[c][row] = sv[c] * id;
    }
    __syncthreads();

    #pragma unroll
    for (int k = 0; k < 2; ++k) {
        int e = tid + k * 256;
        int row = e >> 3, seg = e & 7;
        int j = jrow[row];
        float a8[8];
        #pragma unroll
        for (int i = 0; i < 8; ++i) a8[i] = 0.f;
        #pragma unroll
        for (int c = 0; c < KS_; ++c) {
            bf16x8 v = *(const bf16x8*)(Opart + ((size_t)(c * B_ + b) * N_ + j) * 256 + og * 64 + seg * 8);
            float wgt = wls[c][row];
            #pragma unroll
            for (int i = 0; i < 8; ++i) a8[i] += wgt * (float)v[i];
        }
        bf16x8 o8;
        #pragma unroll
        for (int i = 0; i < 8; ++i) o8[i] = (bf16)a8[i];
        *(bf16x8*)&lds[row * 72 + seg * 8] = o8;
    }
    __syncthreads();

    const int pl  = tid & 63;
    const int og2 = tid >> 6;
    #pragma unroll
    for (int k = 0; k < 8; ++k) {
        int o_loc = og2 * 16 + k * 2;
        bf16x2 v2 = *(const bf16x2*)&lds[pl * 72 + o_loc];
        int o = og * 64 + o_loc;
        size_t a = ((size_t)b * 256 + o) * N_ + p0 + pl;
        out[a]      += (float)v2[0];
        out[a + N_] += (float)v2[1];
    }
}

// ---------------------------------------------------------------------------
extern "C" void kernel_launch(void* const* d_in, const int* in_sizes, int n_in,
                              void* d_out, int out_size, void* d_ws, size_t ws_size,
                              hipStream_t stream) {
    const float* pcd  = (const float*)d_in[0];
    const float* sel  = (const float*)d_in[1];
    const float* drop = (const float*)d_in[2];
    const int*   isel = (const int*)d_in[3];
    const int*   idrp = (const int*)d_in[4];
    const float* Wq   = (const float*)d_in[5];
    const float* Wk   = (const float*)d_in[6];
    const float* Wv   = (const float*)d_in[7];
    const float* Ws   = (const float*)d_in[8];
    float* out = (float*)d_out;

    const size_t MB = 1024 * 1024;
    // ws: qT 4MB | kTt 4MB | vTt 4MB | Opart KS*4MB | S_ws KS*128KB | inv 32KB
    char*  ws    = (char*)d_ws;
    bf16*  qT    = (bf16*)(ws);
    bf16*  kTt   = (bf16*)(ws + 4 * MB);
    bf16*  vTt   = (bf16*)(ws + 8 * MB);
    bf16*  Opart = (bf16*)(ws + 12 * MB);
    float* S_ws  = (float*)(ws + (12 + KS_ * 4) * MB);
    int*   inv   = (int*)(ws + (12 + KS_ * 4) * MB + KS_ * 128 * 1024);
    bf16*  Wbf   = Opart;   // aliases Opart: read by qkv BEFORE attn writes it

    prep_kernel<<<dim3(160), 256, 0, stream>>>(isel, idrp, Wq, Wk, Wv, Ws, inv, Wbf);
    qkv_mfma_kernel<<<dim3(32, 8, B_), 256, 0, stream>>>(pcd, sel, drop, Wbf,
                                                         qT, kTt, vTt, out);
    attn_kernel<<<dim3(32 * 16 * KS_), 256, 0, stream>>>(qT, kTt, vTt, Opart, S_ws);
    scatter_kernel<<<dim3(32, 4, B_), 256, 0, stream>>>(Opart, S_ws, inv, out);
}